// Round 10
// baseline (1145.496 us; speedup 1.0000x reference)
//
#include <hip/hip_runtime.h>
#include <hip/hip_bf16.h>

#define NN    50000
#define ROWS  50048   // NN padded to 128 (GEMM row tiles)
#define DIN   128
#define DHID  256
#define DOH   128
#define DCH   64
#define DOUT  7
#define NE    500000
#define OFFS  50004   // stride of per-type offset arrays (NN+1 padded)
#define EPSV  1e-5f
#define LDAGG 1024    // aggbuf stride (shorts)

typedef unsigned int uint;
typedef unsigned short ushort;
using short8 = __attribute__((ext_vector_type(8))) short;
using f32x4  = __attribute__((ext_vector_type(4))) float;

__device__ inline float b2f(ushort u) {
    union { float f; uint i; } v; v.i = ((uint)u) << 16; return v.f;
}
__device__ inline ushort f2b(float f) {
    union { float f; uint u; } v; v.f = f;
    uint r = v.u + 0x7fff + ((v.u >> 16) & 1);
    return (ushort)(r >> 16);
}
__device__ inline uint packb(float a, float b) {
    return (uint)f2b(a) | ((uint)f2b(b) << 16);
}
__device__ inline float lo16f(uint v) {
    union { uint u; float f; } t; t.u = v << 16; return t.f;
}
__device__ inline float hi16f(uint v) {
    union { uint u; float f; } t; t.u = v & 0xffff0000u; return t.f;
}

// async 16B global -> LDS (linear dest: wave-uniform base + lane*16)
__device__ inline void gl16(const ushort* g, ushort* l) {
    __builtin_amdgcn_global_load_lds(
        (const __attribute__((address_space(1))) unsigned int*)g,
        (__attribute__((address_space(3))) unsigned int*)l, 16, 0, 0);
}

#define ACC8(A, V) do { \
    A[0] += lo16f(V.x); A[1] += hi16f(V.x); \
    A[2] += lo16f(V.y); A[3] += hi16f(V.y); \
    A[4] += lo16f(V.z); A[5] += hi16f(V.z); \
    A[6] += lo16f(V.w); A[7] += hi16f(V.w); } while (0)

// ---------------- CSR build (ILP-4) ----------------

__global__ void count_k(const int* __restrict__ d0, const int* __restrict__ d1,
                        const int* __restrict__ d2, const int* __restrict__ d3,
                        int* __restrict__ cnt) {
    int t = blockIdx.y;
    const int* d = (t == 0) ? d0 : (t == 1) ? d1 : (t == 2) ? d2 : d3;
    int base = blockIdx.x * 1024 + threadIdx.x;
    int* c = cnt + t * NN;
    #pragma unroll
    for (int k = 0; k < 4; ++k) {
        int i = base + k * 256;
        if (i < NE) atomicAdd(&c[d[i]], 1);
    }
}

// exclusive scan of cnt -> off (stride OFFS) AND cursor (stride NN)
__global__ __launch_bounds__(1024)
void scan_k(const int* __restrict__ cnt, int* __restrict__ off,
            int* __restrict__ cursor) {
    const int* c = cnt + blockIdx.x * NN;
    int* o = off + blockIdx.x * OFFS;
    int* cu = cursor + blockIdx.x * NN;
    __shared__ int wsums[16];
    int lane = threadIdx.x & 63, wid = threadIdx.x >> 6;
    int carry = 0;
    for (int base = 0; base < NN; base += 1024) {
        int i = base + threadIdx.x;
        int v = (i < NN) ? c[i] : 0;
        int x = v;
        #pragma unroll
        for (int s = 1; s < 64; s <<= 1) {
            int t = __shfl_up(x, s);
            if (lane >= s) x += t;
        }
        if (lane == 63) wsums[wid] = x;
        __syncthreads();
        if (wid == 0) {
            int wv = (lane < 16) ? wsums[lane] : 0;
            #pragma unroll
            for (int s = 1; s < 16; s <<= 1) {
                int t = __shfl_up(wv, s);
                if (lane >= s) wv += t;
            }
            if (lane < 16) wsums[lane] = wv;
        }
        __syncthreads();
        int wprev = (wid == 0) ? 0 : wsums[wid - 1];
        if (i < NN) {
            int ex = carry + wprev + x - v;
            o[i] = ex;
            cu[i] = ex;
        }
        carry += wsums[15];
        __syncthreads();
    }
    if (threadIdx.x == 0) o[NN] = carry;
}

__global__ void scatter_k(const int* __restrict__ e0, const int* __restrict__ e1,
                          const int* __restrict__ e2, const int* __restrict__ e3,
                          int* __restrict__ cursor, ushort* __restrict__ sorted) {
    int t = blockIdx.y;
    const int* e = (t == 0) ? e0 : (t == 1) ? e1 : (t == 2) ? e2 : e3;
    int* cur = cursor + t * NN;
    ushort* so = sorted + (size_t)t * NE;
    int base = blockIdx.x * 1024 + threadIdx.x;
    #pragma unroll
    for (int k = 0; k < 4; ++k) {
        int i = base + k * 256;
        if (i < NE) {
            int src = e[i], dst = e[NE + i];
            int p = atomicAdd(&cur[dst], 1);
            so[p] = (ushort)src;
        }
    }
}

// ---------------- merged weight prep + xconv (one dispatch) ----------------
// Layer planes: Bt[n][k2], k2 = [hi(Wl0..Wl3|sumWr) | lo(same)], KA=5*Din.
// Head planes:  Bt[n][3K] = [Wh|Wh|Wl]. Biases summed over 4 types.

__device__ inline void wprep_layer_body(const float* __restrict__ Wl,
                                        const float* __restrict__ Wr,
                                        ushort* __restrict__ Bt, int Din, int i) {
    int KA = 5 * Din, K2 = 2 * KA;
    int n = i / KA, k = i - n * KA;
    float v;
    if (k < 4 * Din) {
        int t = k / Din, c = k - t * Din;
        v = Wl[((size_t)t * Din + c) * 256 + n];
    } else {
        int c = k - 4 * Din;
        v = Wr[(size_t)c * 256 + n] + Wr[((size_t)Din + c) * 256 + n]
          + Wr[((size_t)2 * Din + c) * 256 + n] + Wr[((size_t)3 * Din + c) * 256 + n];
    }
    ushort hi = f2b(v);
    Bt[(size_t)n * K2 + k] = hi;
    Bt[(size_t)n * K2 + KA + k] = f2b(v - b2f(hi));
}

__device__ inline void wprep_t3_body(const float* __restrict__ W,
                                     ushort* __restrict__ Bt, int N, int K, int i) {
    int K3 = 3 * K;
    int n = i / K3, k3 = i - n * K3;
    int k = (k3 < K) ? k3 : ((k3 < 2 * K) ? k3 - K : k3 - 2 * K);
    float v = W[(size_t)k * N + n];
    ushort hi = f2b(v);
    Bt[i] = (k3 < 2 * K) ? hi : f2b(v - b2f(hi));
}

__global__ __launch_bounds__(256)
void prep_k(const float* __restrict__ Wl0, const float* __restrict__ Wr0,
            const float* __restrict__ Wl, const float* __restrict__ Wr,
            const float* __restrict__ bl0, const float* __restrict__ bl,
            const float* __restrict__ lin_W, const float* __restrict__ pW1,
            const float* __restrict__ pW2, const float* __restrict__ cW1,
            const float* __restrict__ x,
            ushort* __restrict__ WBt0, ushort* __restrict__ WBt1,
            ushort* __restrict__ WBt2, ushort* __restrict__ BtLin,
            ushort* __restrict__ BtP1, ushort* __restrict__ BtP2,
            ushort* __restrict__ BtC1, float* __restrict__ bsum,
            ushort* __restrict__ aggbuf) {
    int b = blockIdx.x;
    int tid = threadIdx.x;
    if (b < 640) {                      // layer0 weights (163840 elems)
        wprep_layer_body(Wl0, Wr0, WBt0, DIN, b * 256 + tid);
    } else if (b < 1920) {              // layer1 weights (327680)
        wprep_layer_body(Wl, Wr, WBt1, DHID, (b - 640) * 256 + tid);
    } else if (b < 3200) {              // layer2 weights
        wprep_layer_body(Wl + 4 * DHID * DHID, Wr + 4 * DHID * DHID, WBt2, DHID,
                         (b - 1920) * 256 + tid);
    } else if (b < 3584) {              // lin 128x768
        wprep_t3_body(lin_W, BtLin, DOH, DHID, (b - 3200) * 256 + tid);
    } else if (b < 3776) {              // pW1 128x384
        wprep_t3_body(pW1, BtP1, DOH, DOH, (b - 3584) * 256 + tid);
    } else if (b < 3968) {              // pW2 128x384
        wprep_t3_body(pW2, BtP2, DOH, DOH, (b - 3776) * 256 + tid);
    } else if (b < 4064) {              // cW1 64x384
        wprep_t3_body(cW1, BtC1, DCH, DOH, (b - 3968) * 256 + tid);
    } else if (b < 4067) {              // bias sums (3 layers)
        int w = b - 4064;
        const float* src = (w == 0) ? bl0 : bl + (size_t)(w - 1) * 4 * DHID;
        bsum[w * 256 + tid] = src[tid] + src[256 + tid] + src[512 + tid] + src[768 + tid];
    } else {                            // xconv: 25000 blocks (6.4M elems)
        int i = (b - 4067) * 256 + tid;
        int node = i >> 7, c = i & 127;
        aggbuf[(size_t)node * LDAGG + 512 + c] = f2b(x[i]);
    }
}

// ---------------- bf16 mean aggregation, lane-split multi-edge ----------------

__global__ __launch_bounds__(256)
void aggrb128_k(const ushort* __restrict__ hsrc,
                const int* __restrict__ off, const ushort* __restrict__ sorted,
                ushort* __restrict__ out) {
    int node = blockIdx.x * 4 + (threadIdx.x >> 6);
    if (node >= NN) return;
    int t = blockIdx.y;
    int l = threadIdx.x & 63;
    int quad = l >> 4, li = l & 15;
    const int* of = off + (size_t)t * OFFS;
    const ushort* so = sorted + (size_t)t * NE;
    int s0 = of[node], s1 = of[node + 1];
    const ushort* hb = hsrc + (size_t)li * 8;
    float a0[8] = {}, a1[8] = {};
    int e = s0 + quad;
    for (; e + 4 < s1; e += 8) {
        uint4 v = *(const uint4*)(hb + (size_t)so[e] * LDAGG);
        uint4 w = *(const uint4*)(hb + (size_t)so[e + 4] * LDAGG);
        ACC8(a0, v);
        ACC8(a1, w);
    }
    if (e < s1) {
        uint4 v = *(const uint4*)(hb + (size_t)so[e] * LDAGG);
        ACC8(a0, v);
    }
    #pragma unroll
    for (int j = 0; j < 8; ++j) {
        a0[j] += a1[j];
        a0[j] += __shfl_xor(a0[j], 16);
        a0[j] += __shfl_xor(a0[j], 32);
    }
    int deg = s1 - s0;
    float inv = 1.f / (float)(deg > 0 ? deg : 1);
    if (quad == 0) {
        uint4 o;
        o.x = packb(a0[0] * inv, a0[1] * inv);
        o.y = packb(a0[2] * inv, a0[3] * inv);
        o.z = packb(a0[4] * inv, a0[5] * inv);
        o.w = packb(a0[6] * inv, a0[7] * inv);
        *(uint4*)(out + (size_t)node * LDAGG + t * 128 + li * 8) = o;
    }
}

__global__ __launch_bounds__(256)
void aggrb256_k(const ushort* __restrict__ hsrc,
                const int* __restrict__ off, const ushort* __restrict__ sorted,
                ushort* __restrict__ out) {
    int node = blockIdx.x * 4 + (threadIdx.x >> 6);
    if (node >= NN) return;
    int t = blockIdx.y;
    int l = threadIdx.x & 63;
    int half = l >> 5, li = l & 31;
    const int* of = off + (size_t)t * OFFS;
    const ushort* so = sorted + (size_t)t * NE;
    int s0 = of[node], s1 = of[node + 1];
    const ushort* hb = hsrc + (size_t)li * 8;
    float a0[8] = {}, a1[8] = {};
    int e = s0 + half;
    for (; e + 2 < s1; e += 4) {
        uint4 v = *(const uint4*)(hb + (size_t)so[e] * 256);
        uint4 w = *(const uint4*)(hb + (size_t)so[e + 2] * 256);
        ACC8(a0, v);
        ACC8(a1, w);
    }
    if (e < s1) {
        uint4 v = *(const uint4*)(hb + (size_t)so[e] * 256);
        ACC8(a0, v);
    }
    #pragma unroll
    for (int j = 0; j < 8; ++j) {
        a0[j] += a1[j];
        a0[j] += __shfl_xor(a0[j], 32);
    }
    int deg = s1 - s0;
    float inv = 1.f / (float)(deg > 0 ? deg : 1);
    if (half == 0) {
        uint4 o;
        o.x = packb(a0[0] * inv, a0[1] * inv);
        o.y = packb(a0[2] * inv, a0[3] * inv);
        o.z = packb(a0[4] * inv, a0[5] * inv);
        o.w = packb(a0[6] * inv, a0[7] * inv);
        *(uint4*)(out + (size_t)node * LDAGG + t * 256 + li * 8) = o;
    }
}

// ---------------- layer MFMA GEMM: stage A once, hi+lo B planes per step ----------
// C[128,256] = A[*,KA] @ (Bhi+Blo)[256,KA]^T, A two-source at ksplit.
// OMODE: 1 bf16 out, 2 split hi|lo out (lo at col+256).

template <int OMODE>
__global__ __launch_bounds__(512)
void lgemm_k(const ushort* __restrict__ A, int lda,
             const ushort* __restrict__ A2, int lda2, int ksplit,
             const ushort* __restrict__ Bt, const float* __restrict__ bias,
             void* __restrict__ Cout, int ldc, int M, int KA) {
    __shared__ ushort lsA[128 * 32];        // 8 KB
    __shared__ ushort lsB[2 * 256 * 32];    // 32 KB (plane 0 = hi, 1 = lo)
    const int tid = threadIdx.x;
    const int l = tid & 63, wid = tid >> 6;
    const int wm = wid / 4, wn = wid % 4;
    const int row0 = blockIdx.x * 128;
    const int K2 = 2 * KA;
    f32x4 acc[4][4] = {};
    for (int kA = 0; kA < KA; kA += 32) {
        const ushort* srcA;
        int lsrc;
        if (kA < ksplit) { srcA = A + kA; lsrc = lda; }
        else             { srcA = A2 + (kA - ksplit); lsrc = lda2; }
        {   // A: 512 chunks, 1 per thread
            int r = tid >> 2, cs = tid & 3;
            int cg = cs ^ (r & 3);
            gl16(srcA + (size_t)(row0 + r) * lsrc + cg * 8, lsA + tid * 8);
        }
        #pragma unroll
        for (int q = 0; q < 4; ++q) {   // B: 2048 chunks (2 planes x 1024)
            int ch = tid + q * 512;
            int p = ch >> 10, rem = ch & 1023;
            int r = rem >> 2, cs = rem & 3;
            int cg = cs ^ (r & 3);
            gl16(Bt + (size_t)r * K2 + p * KA + kA + cg * 8, lsB + ch * 8);
        }
        __syncthreads();
        short8 af[4], bh[4], blo[4];
        #pragma unroll
        for (int fm = 0; fm < 4; ++fm) {
            int R = wm * 64 + fm * 16 + (l & 15);
            int c = (l >> 4) ^ (R & 3);
            af[fm] = *(const short8*)(lsA + (R * 4 + c) * 8);
        }
        #pragma unroll
        for (int fn = 0; fn < 4; ++fn) {
            int R = wn * 64 + fn * 16 + (l & 15);
            int c = (l >> 4) ^ (R & 3);
            bh[fn]  = *(const short8*)(lsB + (R * 4 + c) * 8);
            blo[fn] = *(const short8*)(lsB + 8192 + (R * 4 + c) * 8);
        }
        #pragma unroll
        for (int fm = 0; fm < 4; ++fm)
            #pragma unroll
            for (int fn = 0; fn < 4; ++fn) {
                acc[fm][fn] = __builtin_amdgcn_mfma_f32_16x16x32_bf16(
                    af[fm], bh[fn], acc[fm][fn], 0, 0, 0);
                acc[fm][fn] = __builtin_amdgcn_mfma_f32_16x16x32_bf16(
                    af[fm], blo[fn], acc[fm][fn], 0, 0, 0);
            }
        __syncthreads();
    }
    #pragma unroll
    for (int fm = 0; fm < 4; ++fm) {
        #pragma unroll
        for (int fn = 0; fn < 4; ++fn) {
            int col = wn * 64 + fn * 16 + (l & 15);
            float bv = bias[col];
            #pragma unroll
            for (int q = 0; q < 4; ++q) {
                int row = row0 + wm * 64 + fm * 16 + (l >> 4) * 4 + q;
                if (row < M) {
                    float v = fmaxf(acc[fm][fn][q] + bv, 0.f);   // layers always ReLU
                    if (OMODE == 1) {
                        ((ushort*)Cout)[(size_t)row * ldc + col] = f2b(v);
                    } else {
                        ushort hv = f2b(v);
                        ((ushort*)Cout)[(size_t)row * ldc + col] = hv;
                        ((ushort*)Cout)[(size_t)row * ldc + col + 256] = f2b(v - b2f(hv));
                    }
                }
            }
        }
    }
}

// ---------------- head MFMA GEMM (two-source A, wrap at KA) ----------------
// OMODE: 0 fp32 out, 1 bf16 out, 2 split hi|lo out (lo at col+BN).

template <int BN, int NWN, bool RELU, int OMODE>
__global__ __launch_bounds__(128 * NWN)
void mgemm_k(const ushort* __restrict__ A, int lda,
             const ushort* __restrict__ A2, int lda2, int ksplit,
             const ushort* __restrict__ Bt, const float* __restrict__ bias,
             void* __restrict__ Cout, int ldc, int M, int K2, int KA) {
    constexpr int T = 128 * NWN;
    __shared__ ushort lsA[128 * 32];
    __shared__ ushort lsB[BN * 32];
    const int tid = threadIdx.x;
    const int l = tid & 63, wid = tid >> 6;
    const int wm = wid / NWN, wn = wid % NWN;
    const int row0 = blockIdx.x * 128;
    f32x4 acc[4][4] = {};
    for (int k0 = 0; k0 < K2; k0 += 32) {
        int kA = (k0 < KA) ? k0 : k0 - KA;
        const ushort* srcA;
        int lsrc;
        if (kA < ksplit) { srcA = A + kA; lsrc = lda; }
        else             { srcA = A2 + (kA - ksplit); lsrc = lda2; }
        #pragma unroll
        for (int q = 0; q < 512 / T; ++q) {
            int ch = tid + q * T;
            int r = ch >> 2, cs = ch & 3;
            int cg = cs ^ (r & 3);
            gl16(srcA + (size_t)(row0 + r) * lsrc + cg * 8, lsA + ch * 8);
        }
        #pragma unroll
        for (int q = 0; q < BN * 4 / T; ++q) {
            int ch = tid + q * T;
            int r = ch >> 2, cs = ch & 3;
            int cg = cs ^ (r & 3);
            gl16(Bt + (size_t)r * K2 + k0 + cg * 8, lsB + ch * 8);
        }
        __syncthreads();
        short8 af[4], bfr[4];
        #pragma unroll
        for (int fm = 0; fm < 4; ++fm) {
            int R = wm * 64 + fm * 16 + (l & 15);
            int c = (l >> 4) ^ (R & 3);
            af[fm] = *(const short8*)(lsA + (R * 4 + c) * 8);
        }
        #pragma unroll
        for (int fn = 0; fn < 4; ++fn) {
            int R = wn * 64 + fn * 16 + (l & 15);
            int c = (l >> 4) ^ (R & 3);
            bfr[fn] = *(const short8*)(lsB + (R * 4 + c) * 8);
        }
        #pragma unroll
        for (int fm = 0; fm < 4; ++fm)
            #pragma unroll
            for (int fn = 0; fn < 4; ++fn)
                acc[fm][fn] = __builtin_amdgcn_mfma_f32_16x16x32_bf16(
                    af[fm], bfr[fn], acc[fm][fn], 0, 0, 0);
        __syncthreads();
    }
    #pragma unroll
    for (int fm = 0; fm < 4; ++fm) {
        #pragma unroll
        for (int fn = 0; fn < 4; ++fn) {
            int col = wn * 64 + fn * 16 + (l & 15);
            float bv = bias[col];
            #pragma unroll
            for (int q = 0; q < 4; ++q) {
                int row = row0 + wm * 64 + fm * 16 + (l >> 4) * 4 + q;
                if (row < M) {
                    float v = acc[fm][fn][q] + bv;
                    if (RELU) v = fmaxf(v, 0.f);
                    if (OMODE == 0) {
                        ((float*)Cout)[(size_t)row * ldc + col] = v;
                    } else if (OMODE == 1) {
                        ((ushort*)Cout)[(size_t)row * ldc + col] = f2b(v);
                    } else {
                        ushort hv = f2b(v);
                        ((ushort*)Cout)[(size_t)row * ldc + col] = hv;
                        ((ushort*)Cout)[(size_t)row * ldc + col + BN] = f2b(v - b2f(hv));
                    }
                }
            }
        }
    }
}

// ---------------- pooling + LayerNorm (lane-half split, split-bf16 out) ----------------

__device__ inline float waveReduceSum(float v) {
    #pragma unroll
    for (int s = 32; s > 0; s >>= 1) v += __shfl_xor(v, s);
    return v;
}

__global__ __launch_bounds__(256)
void poolln_k(const float* __restrict__ hL, const int* __restrict__ off,
              const ushort* __restrict__ sorted, const float* __restrict__ g,
              const float* __restrict__ b, ushort* __restrict__ outS) {
    int node = blockIdx.x * 4 + (threadIdx.x >> 6);
    if (node >= NN) return;
    int l = threadIdx.x & 63;
    int half = l >> 5, li = l & 31;
    int s0 = off[node], s1 = off[node + 1];
    const float* hb = hL + (size_t)li * 4;
    float4 self = *(const float4*)(hb + (size_t)node * DOH);
    float a0[4] = {}, a1[4] = {};
    int e = s0 + half;
    for (; e + 2 < s1; e += 4) {
        float4 v = *(const float4*)(hb + (size_t)sorted[e] * DOH);
        float4 w = *(const float4*)(hb + (size_t)sorted[e + 2] * DOH);
        a0[0] += v.x; a0[1] += v.y; a0[2] += v.z; a0[3] += v.w;
        a1[0] += w.x; a1[1] += w.y; a1[2] += w.z; a1[3] += w.w;
    }
    if (e < s1) {
        float4 v = *(const float4*)(hb + (size_t)sorted[e] * DOH);
        a0[0] += v.x; a0[1] += v.y; a0[2] += v.z; a0[3] += v.w;
    }
    #pragma unroll
    for (int j = 0; j < 4; ++j) {
        a0[j] += a1[j];
        a0[j] += __shfl_xor(a0[j], 32);
    }
    int deg = s1 - s0;
    float inv = 1.f / (float)(deg > 0 ? deg : 1);
    float v0 = (self.x + a0[0]) * inv;
    float v1 = (self.y + a0[1]) * inv;
    float v2 = (self.z + a0[2]) * inv;
    float v3 = (self.w + a0[3]) * inv;
    // every column's value is held by exactly 2 lanes -> divide by 2*DOH
    float mean = waveReduceSum(v0 + v1 + v2 + v3) * (1.f / (2 * DOH));
    float ex2  = waveReduceSum(v0 * v0 + v1 * v1 + v2 * v2 + v3 * v3) * (1.f / (2 * DOH));
    float rst = rsqrtf(ex2 - mean * mean + EPSV);
    float4 gv = *(const float4*)(g + li * 4);
    float4 bv = *(const float4*)(b + li * 4);
    float o0 = (v0 - mean) * rst * gv.x + bv.x;
    float o1 = (v1 - mean) * rst * gv.y + bv.y;
    float o2 = (v2 - mean) * rst * gv.z + bv.z;
    float o3 = (v3 - mean) * rst * gv.w + bv.w;
    if (half == 0) {
        ushort* row = outS + (size_t)node * 256;
        ushort h0 = f2b(o0), h1 = f2b(o1), h2 = f2b(o2), h3 = f2b(o3);
        uint2 hi, lo;
        hi.x = (uint)h0 | ((uint)h1 << 16);
        hi.y = (uint)h2 | ((uint)h3 << 16);
        lo.x = packb(o0 - b2f(h0), o1 - b2f(h1));
        lo.y = packb(o2 - b2f(h2), o3 - b2f(h3));
        *(uint2*)(row + li * 4)       = hi;
        *(uint2*)(row + 128 + li * 4) = lo;
    }
}

// LayerNorm in place on split hi|lo buffer [M,256]
__global__ __launch_bounds__(256)
void lns_k(ushort* __restrict__ hS, const float* __restrict__ g,
           const float* __restrict__ b) {
    int node = blockIdx.x * 4 + (threadIdx.x >> 6);
    if (node >= NN) return;
    int l = threadIdx.x & 63;
    ushort* row = hS + (size_t)node * 256;
    uint hh = *(uint*)(row + 2 * l);
    uint ll = *(uint*)(row + 128 + 2 * l);
    float v0 = b2f((ushort)hh) + b2f((ushort)ll);
    float v1 = b2f((ushort)(hh >> 16)) + b2f((ushort)(ll >> 16));
    float mean = waveReduceSum(v0 + v1) * (1.f / DOH);
    float ex2  = waveReduceSum(v0 * v0 + v1 * v1) * (1.f / DOH);
    float rst = rsqrtf(ex2 - mean * mean + EPSV);
    float o0 = (v0 - mean) * rst * g[2 * l] + b[2 * l];
    float o1 = (v1 - mean) * rst * g[2 * l + 1] + b[2 * l + 1];
    ushort h0 = f2b(o0), h1 = f2b(o1);
    ushort lo0 = f2b(o0 - b2f(h0)), lo1 = f2b(o1 - b2f(h1));
    *(uint*)(row + 2 * l)       = (uint)h0 | ((uint)h1 << 16);
    *(uint*)(row + 128 + 2 * l) = (uint)lo0 | ((uint)lo1 << 16);
}

// ---------------- BatchNorm stats + final classifier ----------------

__global__ __launch_bounds__(256)
void bnstat_k(const float* __restrict__ z, float* __restrict__ sums, int M) {
    int col = threadIdx.x & 63;
    int rgrp = threadIdx.x >> 6;
    float s = 0.f, s2 = 0.f;
    for (int r = blockIdx.x * 4 + rgrp; r < M; r += gridDim.x * 4) {
        float v = z[(size_t)r * DCH + col];
        s += v; s2 += v * v;
    }
    __shared__ float sh[2][4][64];
    sh[0][rgrp][col] = s;
    sh[1][rgrp][col] = s2;
    __syncthreads();
    if (rgrp == 0) {
        s  = sh[0][0][col] + sh[0][1][col] + sh[0][2][col] + sh[0][3][col];
        s2 = sh[1][0][col] + sh[1][1][col] + sh[1][2][col] + sh[1][3][col];
        atomicAdd(&sums[col], s);
        atomicAdd(&sums[64 + col], s2);
    }
}

__global__ __launch_bounds__(256)
void final_k(const float* __restrict__ z, const float* __restrict__ sums,
             const float* __restrict__ bn_g, const float* __restrict__ bn_b,
             const float* __restrict__ cW2, const float* __restrict__ cb2,
             float* __restrict__ out, int M) {
    int row = blockIdx.x * 4 + (threadIdx.x >> 6);
    int lane = threadIdx.x & 63;
    if (row >= M) return;
    float zv = z[(size_t)row * DCH + lane];
    float mean = sums[lane] * (1.f / M);
    float var = sums[64 + lane] * (1.f / M) - mean * mean;
    float zb = (zv - mean) * rsqrtf(var + EPSV) * bn_g[lane] + bn_b[lane];
    float logit[DOUT];
    #pragma unroll
    for (int o = 0; o < DOUT; ++o) {
        float p = zb * cW2[lane * DOUT + o];
        #pragma unroll
        for (int s = 32; s > 0; s >>= 1) p += __shfl_xor(p, s);
        logit[o] = p + cb2[o];
    }
    float mx = logit[0];
    #pragma unroll
    for (int o = 1; o < DOUT; ++o) mx = fmaxf(mx, logit[o]);
    float den = 0.f;
    #pragma unroll
    for (int o = 0; o < DOUT; ++o) { logit[o] = expf(logit[o] - mx); den += logit[o]; }
    float inv = 1.f / den;
    if (lane == 0) {
        #pragma unroll
        for (int o = 0; o < DOUT; ++o) out[(size_t)row * DOUT + o] = logit[o] * inv;
    }
}

// ---------------- orchestration ----------------

extern "C" void kernel_launch(void* const* d_in, const int* in_sizes, int n_in,
                              void* d_out, int out_size, void* d_ws, size_t ws_size,
                              hipStream_t stream) {
    const float* x     = (const float*)d_in[0];
    const int* eptr[4] = {(const int*)d_in[1], (const int*)d_in[2],
                          (const int*)d_in[3], (const int*)d_in[4]};
    const float* Wl0   = (const float*)d_in[5];
    const float* bl0   = (const float*)d_in[6];
    const float* Wr0   = (const float*)d_in[7];
    const float* Wl    = (const float*)d_in[8];
    const float* bl    = (const float*)d_in[9];
    const float* Wr    = (const float*)d_in[10];
    const float* lin_W = (const float*)d_in[11];
    const float* lin_b = (const float*)d_in[12];
    const float* nrm_g = (const float*)d_in[13];
    const float* nrm_b = (const float*)d_in[14];
    const float* pW1   = (const float*)d_in[15];
    const float* pb1   = (const float*)d_in[16];
    const float* pln_g = (const float*)d_in[17];
    const float* pln_b = (const float*)d_in[18];
    const float* pW2   = (const float*)d_in[19];
    const float* pb2   = (const float*)d_in[20];
    const float* cW1   = (const float*)d_in[21];
    const float* cb1   = (const float*)d_in[22];
    const float* bn_g  = (const float*)d_in[23];
    const float* bn_b  = (const float*)d_in[24];
    const float* cW2   = (const float*)d_in[25];
    const float* cb2   = (const float*)d_in[26];

    size_t wo = 0;
    auto alloc = [&](size_t bytes) -> void* {
        void* p = (char*)d_ws + wo;
        wo += (bytes + 255) & ~(size_t)255;
        return p;
    };
    int* off      = (int*)alloc(4 * OFFS * sizeof(int));
    int* cursor   = (int*)alloc(4 * NN * sizeof(int));
    ushort* sorted = (ushort*)alloc((size_t)4 * NE * sizeof(ushort));
    ushort* WBt0  = (ushort*)alloc((size_t)256 * 1280 * 2);
    ushort* WBt1  = (ushort*)alloc((size_t)256 * 2560 * 2);
    ushort* WBt2  = (ushort*)alloc((size_t)256 * 2560 * 2);
    ushort* BtLin = (ushort*)alloc((size_t)128 * 768 * 2);
    ushort* BtP1  = (ushort*)alloc((size_t)128 * 384 * 2);
    ushort* BtP2  = (ushort*)alloc((size_t)128 * 384 * 2);
    ushort* BtC1  = (ushort*)alloc((size_t)64 * 384 * 2);
    float* bsum   = (float*)alloc(3 * 256 * sizeof(float));
    float* bnsum  = (float*)alloc(128 * sizeof(float));
    ushort* aggbuf = (ushort*)alloc((size_t)ROWS * LDAGG * 2); // 102.5 MB
    ushort* hc1   = (ushort*)alloc((size_t)ROWS * 256 * 2);    // 25.6 MB
    ushort* hc2   = (ushort*)alloc((size_t)ROWS * 256 * 2);    // 25.6 MB

    // overlays (sequenced by stream order):
    float*  hL  = (float*)hc1;                                  // after hc1 dead (lin out)
    ushort* hPs = hc2;                                          // after hc2 dead (poolln out)
    ushort* hQs = aggbuf;                                       // after aggbuf/z3 dead
    ushort* hRs = (ushort*)((char*)aggbuf + ((size_t)32 << 20));
    float*  z   = (float*)((char*)aggbuf + ((size_t)64 << 20));

    const int EB4 = (NE + 1023) / 1024;   // ILP-4 edge blocks
    const int GX = (NN + 127) / 128;      // 391 MFMA row tiles
    const int AGG = (NN + 3) / 4;         // 12500

    // --- merged weight prep + xconv (independent of CSR) ---
    prep_k<<<4067 + 25000, 256, 0, stream>>>(
        Wl0, Wr0, Wl, Wr, bl0, bl, lin_W, pW1, pW2, cW1, x,
        WBt0, WBt1, WBt2, BtLin, BtP1, BtP2, BtC1, bsum, aggbuf);

    // --- CSR build ---
    hipMemsetAsync(cursor, 0, 4 * NN * sizeof(int), stream);
    count_k<<<dim3(EB4, 4), 256, 0, stream>>>(eptr[0] + NE, eptr[1] + NE,
                                              eptr[2] + NE, eptr[3] + NE, cursor);
    scan_k<<<4, 1024, 0, stream>>>(cursor, off, cursor);
    scatter_k<<<dim3(EB4, 4), 256, 0, stream>>>(eptr[0], eptr[1], eptr[2], eptr[3],
                                                cursor, sorted);

    // --- layer 0: gather from aggbuf+512, GEMM single-source ---
    aggrb128_k<<<dim3(AGG, 4), 256, 0, stream>>>(aggbuf + 512, off, sorted, aggbuf);
    lgemm_k<1><<<GX, 512, 0, stream>>>(
        aggbuf, LDAGG, aggbuf, LDAGG, 640, WBt0, bsum, (void*)hc1, 256, NN, 640);

    // --- layers 1,2: gather from compact hc, GEMM two-source (agg | compact h) ---
    aggrb256_k<<<dim3(AGG, 4), 256, 0, stream>>>(hc1, off, sorted, aggbuf);
    lgemm_k<1><<<GX, 512, 0, stream>>>(
        aggbuf, LDAGG, hc1, 256, 1024, WBt1, bsum + 256, (void*)hc2, 256, NN, 1280);
    aggrb256_k<<<dim3(AGG, 4), 256, 0, stream>>>(hc2, off, sorted, aggbuf);
    lgemm_k<2><<<GX, 512, 0, stream>>>(   // split z3 into aggbuf cols 0:512 (own rows)
        aggbuf, LDAGG, hc2, 256, 1024, WBt2, bsum + 512, (void*)aggbuf, LDAGG, NN, 1280);

    // --- lin head: hL fp32 = z3 @ lin_W + lin_b (split-A x split-W MFMA) ---
    mgemm_k<128, 2, false, 0><<<GX, 256, 0, stream>>>(
        aggbuf, LDAGG, aggbuf, LDAGG, 512, BtLin, lin_b, (void*)hL, DOH, NN, 768, 512);

    // --- onset pooling + LayerNorm -> hPs (split) ---
    poolln_k<<<AGG, 256, 0, stream>>>(hL, off, sorted, nrm_g, nrm_b, hPs);

    // --- pool MLP (split-A x split-W MFMA) ---
    mgemm_k<128, 2, true, 2><<<GX, 256, 0, stream>>>(
        hPs, 256, hPs, 256, 256, BtP1, pb1, (void*)hQs, 256, NN, 384, 256);
    lns_k<<<AGG, 256, 0, stream>>>(hQs, pln_g, pln_b);
    mgemm_k<128, 2, false, 2><<<GX, 256, 0, stream>>>(
        hQs, 256, hQs, 256, 256, BtP2, pb2, (void*)hRs, 256, NN, 384, 256);

    // --- classifier: z fp32 = relu(hRs @ cW1 + cb1); BN stats; final ---
    mgemm_k<64, 1, true, 0><<<GX, 128, 0, stream>>>(
        hRs, 256, hRs, 256, 256, BtC1, cb1, (void*)z, DCH, NN, 384, 256);
    hipMemsetAsync(bnsum, 0, 128 * sizeof(float), stream);
    bnstat_k<<<256, 256, 0, stream>>>(z, bnsum, NN);
    final_k<<<AGG, 256, 0, stream>>>(z, bnsum, bn_g, bn_b, cW2, cb2,
                                     (float*)d_out, NN);
}

// Round 11
// 1088.862 us; speedup vs baseline: 1.0520x; 1.0520x over previous
//
#include <hip/hip_runtime.h>
#include <hip/hip_bf16.h>

#define NN    50000
#define ROWS  50048   // NN padded to 128 (GEMM row tiles)
#define DIN   128
#define DHID  256
#define DOH   128
#define DCH   64
#define DOUT  7
#define NE    500000
#define OFFS  50004   // stride of per-type offset arrays (NN+1 padded)
#define EPSV  1e-5f
#define LDAGG 1024    // aggbuf stride (shorts)

typedef unsigned int uint;
typedef unsigned short ushort;
using short8 = __attribute__((ext_vector_type(8))) short;
using f32x4  = __attribute__((ext_vector_type(4))) float;

__device__ inline float b2f(ushort u) {
    union { float f; uint i; } v; v.i = ((uint)u) << 16; return v.f;
}
__device__ inline ushort f2b(float f) {
    union { float f; uint u; } v; v.f = f;
    uint r = v.u + 0x7fff + ((v.u >> 16) & 1);
    return (ushort)(r >> 16);
}
__device__ inline uint packb(float a, float b) {
    return (uint)f2b(a) | ((uint)f2b(b) << 16);
}
__device__ inline float lo16f(uint v) {
    union { uint u; float f; } t; t.u = v << 16; return t.f;
}
__device__ inline float hi16f(uint v) {
    union { uint u; float f; } t; t.u = v & 0xffff0000u; return t.f;
}

// async 16B global -> LDS (linear dest: wave-uniform base + lane*16)
__device__ inline void gl16(const ushort* g, ushort* l) {
    __builtin_amdgcn_global_load_lds(
        (const __attribute__((address_space(1))) unsigned int*)g,
        (__attribute__((address_space(3))) unsigned int*)l, 16, 0, 0);
}

#define ACC8(A, V) do { \
    A[0] += lo16f(V.x); A[1] += hi16f(V.x); \
    A[2] += lo16f(V.y); A[3] += hi16f(V.y); \
    A[4] += lo16f(V.z); A[5] += hi16f(V.z); \
    A[6] += lo16f(V.w); A[7] += hi16f(V.w); } while (0)

// ---------------- CSR build (1 edge/thread — round-7 proven form) ----------------

__global__ void count_k(const int* __restrict__ d0, const int* __restrict__ d1,
                        const int* __restrict__ d2, const int* __restrict__ d3,
                        int* __restrict__ cnt) {
    int i = blockIdx.x * blockDim.x + threadIdx.x;
    if (i >= NE) return;
    int t = blockIdx.y;
    const int* d = (t == 0) ? d0 : (t == 1) ? d1 : (t == 2) ? d2 : d3;
    atomicAdd(&cnt[t * NN + d[i]], 1);
}

// exclusive scan of cnt -> off (stride OFFS) AND cursor (stride NN)
__global__ __launch_bounds__(1024)
void scan_k(const int* __restrict__ cnt, int* __restrict__ off,
            int* __restrict__ cursor) {
    const int* c = cnt + blockIdx.x * NN;
    int* o = off + blockIdx.x * OFFS;
    int* cu = cursor + blockIdx.x * NN;
    __shared__ int wsums[16];
    int lane = threadIdx.x & 63, wid = threadIdx.x >> 6;
    int carry = 0;
    for (int base = 0; base < NN; base += 1024) {
        int i = base + threadIdx.x;
        int v = (i < NN) ? c[i] : 0;
        int x = v;
        #pragma unroll
        for (int s = 1; s < 64; s <<= 1) {
            int t = __shfl_up(x, s);
            if (lane >= s) x += t;
        }
        if (lane == 63) wsums[wid] = x;
        __syncthreads();
        if (wid == 0) {
            int wv = (lane < 16) ? wsums[lane] : 0;
            #pragma unroll
            for (int s = 1; s < 16; s <<= 1) {
                int t = __shfl_up(wv, s);
                if (lane >= s) wv += t;
            }
            if (lane < 16) wsums[lane] = wv;
        }
        __syncthreads();
        int wprev = (wid == 0) ? 0 : wsums[wid - 1];
        if (i < NN) {
            int ex = carry + wprev + x - v;
            o[i] = ex;
            cu[i] = ex;
        }
        carry += wsums[15];
        __syncthreads();
    }
    if (threadIdx.x == 0) o[NN] = carry;
}

__global__ void scatter_k(const int* __restrict__ e0, const int* __restrict__ e1,
                          const int* __restrict__ e2, const int* __restrict__ e3,
                          int* __restrict__ cursor, ushort* __restrict__ sorted) {
    int i = blockIdx.x * blockDim.x + threadIdx.x;
    if (i >= NE) return;
    int t = blockIdx.y;
    const int* e = (t == 0) ? e0 : (t == 1) ? e1 : (t == 2) ? e2 : e3;
    int src = e[i], dst = e[NE + i];
    int p = atomicAdd(&cursor[t * NN + dst], 1);
    sorted[(size_t)t * NE + p] = (ushort)src;
}

// ---------------- merged weight prep + xconv (one dispatch) ----------------
// Layer planes: Bt[n][k2], k2 = [hi(Wl0..Wl3|sumWr) | lo(same)], KA=5*Din.
// Head planes:  Bt[n][3K] = [Wh|Wh|Wl]. Biases summed over 4 types.

__device__ inline void wprep_layer_body(const float* __restrict__ Wl,
                                        const float* __restrict__ Wr,
                                        ushort* __restrict__ Bt, int Din, int i) {
    int KA = 5 * Din, K2 = 2 * KA;
    int n = i / KA, k = i - n * KA;
    float v;
    if (k < 4 * Din) {
        int t = k / Din, c = k - t * Din;
        v = Wl[((size_t)t * Din + c) * 256 + n];
    } else {
        int c = k - 4 * Din;
        v = Wr[(size_t)c * 256 + n] + Wr[((size_t)Din + c) * 256 + n]
          + Wr[((size_t)2 * Din + c) * 256 + n] + Wr[((size_t)3 * Din + c) * 256 + n];
    }
    ushort hi = f2b(v);
    Bt[(size_t)n * K2 + k] = hi;
    Bt[(size_t)n * K2 + KA + k] = f2b(v - b2f(hi));
}

__device__ inline void wprep_t3_body(const float* __restrict__ W,
                                     ushort* __restrict__ Bt, int N, int K, int i) {
    int K3 = 3 * K;
    int n = i / K3, k3 = i - n * K3;
    int k = (k3 < K) ? k3 : ((k3 < 2 * K) ? k3 - K : k3 - 2 * K);
    float v = W[(size_t)k * N + n];
    ushort hi = f2b(v);
    Bt[i] = (k3 < 2 * K) ? hi : f2b(v - b2f(hi));
}

__global__ __launch_bounds__(256)
void prep_k(const float* __restrict__ Wl0, const float* __restrict__ Wr0,
            const float* __restrict__ Wl, const float* __restrict__ Wr,
            const float* __restrict__ bl0, const float* __restrict__ bl,
            const float* __restrict__ lin_W, const float* __restrict__ pW1,
            const float* __restrict__ pW2, const float* __restrict__ cW1,
            const float* __restrict__ x,
            ushort* __restrict__ WBt0, ushort* __restrict__ WBt1,
            ushort* __restrict__ WBt2, ushort* __restrict__ BtLin,
            ushort* __restrict__ BtP1, ushort* __restrict__ BtP2,
            ushort* __restrict__ BtC1, float* __restrict__ bsum,
            ushort* __restrict__ aggbuf) {
    int b = blockIdx.x;
    int tid = threadIdx.x;
    if (b < 640) {                      // layer0 weights (163840 elems)
        wprep_layer_body(Wl0, Wr0, WBt0, DIN, b * 256 + tid);
    } else if (b < 1920) {              // layer1 weights (327680)
        wprep_layer_body(Wl, Wr, WBt1, DHID, (b - 640) * 256 + tid);
    } else if (b < 3200) {              // layer2 weights
        wprep_layer_body(Wl + 4 * DHID * DHID, Wr + 4 * DHID * DHID, WBt2, DHID,
                         (b - 1920) * 256 + tid);
    } else if (b < 3584) {              // lin 128x768
        wprep_t3_body(lin_W, BtLin, DOH, DHID, (b - 3200) * 256 + tid);
    } else if (b < 3776) {              // pW1 128x384
        wprep_t3_body(pW1, BtP1, DOH, DOH, (b - 3584) * 256 + tid);
    } else if (b < 3968) {              // pW2 128x384
        wprep_t3_body(pW2, BtP2, DOH, DOH, (b - 3776) * 256 + tid);
    } else if (b < 4064) {              // cW1 64x384
        wprep_t3_body(cW1, BtC1, DCH, DOH, (b - 3968) * 256 + tid);
    } else if (b < 4067) {              // bias sums (3 layers)
        int w = b - 4064;
        const float* src = (w == 0) ? bl0 : bl + (size_t)(w - 1) * 4 * DHID;
        bsum[w * 256 + tid] = src[tid] + src[256 + tid] + src[512 + tid] + src[768 + tid];
    } else {                            // xconv: 25000 blocks (6.4M elems)
        int i = (b - 4067) * 256 + tid;
        int node = i >> 7, c = i & 127;
        aggbuf[(size_t)node * LDAGG + 512 + c] = f2b(x[i]);
    }
}

// ---------------- bf16 mean aggregation, lane-split multi-edge ----------------

__global__ __launch_bounds__(256)
void aggrb128_k(const ushort* __restrict__ hsrc,
                const int* __restrict__ off, const ushort* __restrict__ sorted,
                ushort* __restrict__ out) {
    int node = blockIdx.x * 4 + (threadIdx.x >> 6);
    if (node >= NN) return;
    int t = blockIdx.y;
    int l = threadIdx.x & 63;
    int quad = l >> 4, li = l & 15;
    const int* of = off + (size_t)t * OFFS;
    const ushort* so = sorted + (size_t)t * NE;
    int s0 = of[node], s1 = of[node + 1];
    const ushort* hb = hsrc + (size_t)li * 8;
    float a0[8] = {}, a1[8] = {};
    int e = s0 + quad;
    for (; e + 4 < s1; e += 8) {
        uint4 v = *(const uint4*)(hb + (size_t)so[e] * LDAGG);
        uint4 w = *(const uint4*)(hb + (size_t)so[e + 4] * LDAGG);
        ACC8(a0, v);
        ACC8(a1, w);
    }
    if (e < s1) {
        uint4 v = *(const uint4*)(hb + (size_t)so[e] * LDAGG);
        ACC8(a0, v);
    }
    #pragma unroll
    for (int j = 0; j < 8; ++j) {
        a0[j] += a1[j];
        a0[j] += __shfl_xor(a0[j], 16);
        a0[j] += __shfl_xor(a0[j], 32);
    }
    int deg = s1 - s0;
    float inv = 1.f / (float)(deg > 0 ? deg : 1);
    if (quad == 0) {
        uint4 o;
        o.x = packb(a0[0] * inv, a0[1] * inv);
        o.y = packb(a0[2] * inv, a0[3] * inv);
        o.z = packb(a0[4] * inv, a0[5] * inv);
        o.w = packb(a0[6] * inv, a0[7] * inv);
        *(uint4*)(out + (size_t)node * LDAGG + t * 128 + li * 8) = o;
    }
}

__global__ __launch_bounds__(256)
void aggrb256_k(const ushort* __restrict__ hsrc,
                const int* __restrict__ off, const ushort* __restrict__ sorted,
                ushort* __restrict__ out) {
    int node = blockIdx.x * 4 + (threadIdx.x >> 6);
    if (node >= NN) return;
    int t = blockIdx.y;
    int l = threadIdx.x & 63;
    int half = l >> 5, li = l & 31;
    const int* of = off + (size_t)t * OFFS;
    const ushort* so = sorted + (size_t)t * NE;
    int s0 = of[node], s1 = of[node + 1];
    const ushort* hb = hsrc + (size_t)li * 8;
    float a0[8] = {}, a1[8] = {};
    int e = s0 + half;
    for (; e + 2 < s1; e += 4) {
        uint4 v = *(const uint4*)(hb + (size_t)so[e] * 256);
        uint4 w = *(const uint4*)(hb + (size_t)so[e + 2] * 256);
        ACC8(a0, v);
        ACC8(a1, w);
    }
    if (e < s1) {
        uint4 v = *(const uint4*)(hb + (size_t)so[e] * 256);
        ACC8(a0, v);
    }
    #pragma unroll
    for (int j = 0; j < 8; ++j) {
        a0[j] += a1[j];
        a0[j] += __shfl_xor(a0[j], 32);
    }
    int deg = s1 - s0;
    float inv = 1.f / (float)(deg > 0 ? deg : 1);
    if (half == 0) {
        uint4 o;
        o.x = packb(a0[0] * inv, a0[1] * inv);
        o.y = packb(a0[2] * inv, a0[3] * inv);
        o.z = packb(a0[4] * inv, a0[5] * inv);
        o.w = packb(a0[6] * inv, a0[7] * inv);
        *(uint4*)(out + (size_t)node * LDAGG + t * 256 + li * 8) = o;
    }
}

// ---------------- layer MFMA GEMM: stage A once, hi+lo B planes per step ----------
// C[128,256] = A[*,KA] @ (Bhi+Blo)[256,KA]^T, A two-source at ksplit.
// OMODE: 1 bf16 out, 2 split hi|lo out (lo at col+256).

template <int OMODE>
__global__ __launch_bounds__(512)
void lgemm_k(const ushort* __restrict__ A, int lda,
             const ushort* __restrict__ A2, int lda2, int ksplit,
             const ushort* __restrict__ Bt, const float* __restrict__ bias,
             void* __restrict__ Cout, int ldc, int M, int KA) {
    __shared__ ushort lsA[128 * 32];        // 8 KB
    __shared__ ushort lsB[2 * 256 * 32];    // 32 KB (plane 0 = hi, 1 = lo)
    const int tid = threadIdx.x;
    const int l = tid & 63, wid = tid >> 6;
    const int wm = wid / 4, wn = wid % 4;
    const int row0 = blockIdx.x * 128;
    const int K2 = 2 * KA;
    f32x4 acc[4][4] = {};
    for (int kA = 0; kA < KA; kA += 32) {
        const ushort* srcA;
        int lsrc;
        if (kA < ksplit) { srcA = A + kA; lsrc = lda; }
        else             { srcA = A2 + (kA - ksplit); lsrc = lda2; }
        {   // A: 512 chunks, 1 per thread
            int r = tid >> 2, cs = tid & 3;
            int cg = cs ^ (r & 3);
            gl16(srcA + (size_t)(row0 + r) * lsrc + cg * 8, lsA + tid * 8);
        }
        #pragma unroll
        for (int q = 0; q < 4; ++q) {   // B: 2048 chunks (2 planes x 1024)
            int ch = tid + q * 512;
            int p = ch >> 10, rem = ch & 1023;
            int r = rem >> 2, cs = rem & 3;
            int cg = cs ^ (r & 3);
            gl16(Bt + (size_t)r * K2 + p * KA + kA + cg * 8, lsB + ch * 8);
        }
        __syncthreads();
        short8 af[4], bh[4], blo[4];
        #pragma unroll
        for (int fm = 0; fm < 4; ++fm) {
            int R = wm * 64 + fm * 16 + (l & 15);
            int c = (l >> 4) ^ (R & 3);
            af[fm] = *(const short8*)(lsA + (R * 4 + c) * 8);
        }
        #pragma unroll
        for (int fn = 0; fn < 4; ++fn) {
            int R = wn * 64 + fn * 16 + (l & 15);
            int c = (l >> 4) ^ (R & 3);
            bh[fn]  = *(const short8*)(lsB + (R * 4 + c) * 8);
            blo[fn] = *(const short8*)(lsB + 8192 + (R * 4 + c) * 8);
        }
        #pragma unroll
        for (int fm = 0; fm < 4; ++fm)
            #pragma unroll
            for (int fn = 0; fn < 4; ++fn) {
                acc[fm][fn] = __builtin_amdgcn_mfma_f32_16x16x32_bf16(
                    af[fm], bh[fn], acc[fm][fn], 0, 0, 0);
                acc[fm][fn] = __builtin_amdgcn_mfma_f32_16x16x32_bf16(
                    af[fm], blo[fn], acc[fm][fn], 0, 0, 0);
            }
        __syncthreads();
    }
    #pragma unroll
    for (int fm = 0; fm < 4; ++fm) {
        #pragma unroll
        for (int fn = 0; fn < 4; ++fn) {
            int col = wn * 64 + fn * 16 + (l & 15);
            float bv = bias[col];
            #pragma unroll
            for (int q = 0; q < 4; ++q) {
                int row = row0 + wm * 64 + fm * 16 + (l >> 4) * 4 + q;
                if (row < M) {
                    float v = fmaxf(acc[fm][fn][q] + bv, 0.f);   // layers always ReLU
                    if (OMODE == 1) {
                        ((ushort*)Cout)[(size_t)row * ldc + col] = f2b(v);
                    } else {
                        ushort hv = f2b(v);
                        ((ushort*)Cout)[(size_t)row * ldc + col] = hv;
                        ((ushort*)Cout)[(size_t)row * ldc + col + 256] = f2b(v - b2f(hv));
                    }
                }
            }
        }
    }
}

// ---------------- head MFMA GEMM (two-source A, wrap at KA) ----------------
// OMODE: 0 fp32 out, 1 bf16 out, 2 split hi|lo out (lo at col+BN).

template <int BN, int NWN, bool RELU, int OMODE>
__global__ __launch_bounds__(128 * NWN)
void mgemm_k(const ushort* __restrict__ A, int lda,
             const ushort* __restrict__ A2, int lda2, int ksplit,
             const ushort* __restrict__ Bt, const float* __restrict__ bias,
             void* __restrict__ Cout, int ldc, int M, int K2, int KA) {
    constexpr int T = 128 * NWN;
    __shared__ ushort lsA[128 * 32];
    __shared__ ushort lsB[BN * 32];
    const int tid = threadIdx.x;
    const int l = tid & 63, wid = tid >> 6;
    const int wm = wid / NWN, wn = wid % NWN;
    const int row0 = blockIdx.x * 128;
    f32x4 acc[4][4] = {};
    for (int k0 = 0; k0 < K2; k0 += 32) {
        int kA = (k0 < KA) ? k0 : k0 - KA;
        const ushort* srcA;
        int lsrc;
        if (kA < ksplit) { srcA = A + kA; lsrc = lda; }
        else             { srcA = A2 + (kA - ksplit); lsrc = lda2; }
        #pragma unroll
        for (int q = 0; q < 512 / T; ++q) {
            int ch = tid + q * T;
            int r = ch >> 2, cs = ch & 3;
            int cg = cs ^ (r & 3);
            gl16(srcA + (size_t)(row0 + r) * lsrc + cg * 8, lsA + ch * 8);
        }
        #pragma unroll
        for (int q = 0; q < BN * 4 / T; ++q) {
            int ch = tid + q * T;
            int r = ch >> 2, cs = ch & 3;
            int cg = cs ^ (r & 3);
            gl16(Bt + (size_t)r * K2 + k0 + cg * 8, lsB + ch * 8);
        }
        __syncthreads();
        short8 af[4], bfr[4];
        #pragma unroll
        for (int fm = 0; fm < 4; ++fm) {
            int R = wm * 64 + fm * 16 + (l & 15);
            int c = (l >> 4) ^ (R & 3);
            af[fm] = *(const short8*)(lsA + (R * 4 + c) * 8);
        }
        #pragma unroll
        for (int fn = 0; fn < 4; ++fn) {
            int R = wn * 64 + fn * 16 + (l & 15);
            int c = (l >> 4) ^ (R & 3);
            bfr[fn] = *(const short8*)(lsB + (R * 4 + c) * 8);
        }
        #pragma unroll
        for (int fm = 0; fm < 4; ++fm)
            #pragma unroll
            for (int fn = 0; fn < 4; ++fn)
                acc[fm][fn] = __builtin_amdgcn_mfma_f32_16x16x32_bf16(
                    af[fm], bfr[fn], acc[fm][fn], 0, 0, 0);
        __syncthreads();
    }
    #pragma unroll
    for (int fm = 0; fm < 4; ++fm) {
        #pragma unroll
        for (int fn = 0; fn < 4; ++fn) {
            int col = wn * 64 + fn * 16 + (l & 15);
            float bv = bias[col];
            #pragma unroll
            for (int q = 0; q < 4; ++q) {
                int row = row0 + wm * 64 + fm * 16 + (l >> 4) * 4 + q;
                if (row < M) {
                    float v = acc[fm][fn][q] + bv;
                    if (RELU) v = fmaxf(v, 0.f);
                    if (OMODE == 0) {
                        ((float*)Cout)[(size_t)row * ldc + col] = v;
                    } else if (OMODE == 1) {
                        ((ushort*)Cout)[(size_t)row * ldc + col] = f2b(v);
                    } else {
                        ushort hv = f2b(v);
                        ((ushort*)Cout)[(size_t)row * ldc + col] = hv;
                        ((ushort*)Cout)[(size_t)row * ldc + col + BN] = f2b(v - b2f(hv));
                    }
                }
            }
        }
    }
}

// ---------------- pooling + LayerNorm (lane-half split, split-bf16 out) ----------------

__device__ inline float waveReduceSum(float v) {
    #pragma unroll
    for (int s = 32; s > 0; s >>= 1) v += __shfl_xor(v, s);
    return v;
}

__global__ __launch_bounds__(256)
void poolln_k(const float* __restrict__ hL, const int* __restrict__ off,
              const ushort* __restrict__ sorted, const float* __restrict__ g,
              const float* __restrict__ b, ushort* __restrict__ outS) {
    int node = blockIdx.x * 4 + (threadIdx.x >> 6);
    if (node >= NN) return;
    int l = threadIdx.x & 63;
    int half = l >> 5, li = l & 31;
    int s0 = off[node], s1 = off[node + 1];
    const float* hb = hL + (size_t)li * 4;
    float4 self = *(const float4*)(hb + (size_t)node * DOH);
    float a0[4] = {}, a1[4] = {};
    int e = s0 + half;
    for (; e + 2 < s1; e += 4) {
        float4 v = *(const float4*)(hb + (size_t)sorted[e] * DOH);
        float4 w = *(const float4*)(hb + (size_t)sorted[e + 2] * DOH);
        a0[0] += v.x; a0[1] += v.y; a0[2] += v.z; a0[3] += v.w;
        a1[0] += w.x; a1[1] += w.y; a1[2] += w.z; a1[3] += w.w;
    }
    if (e < s1) {
        float4 v = *(const float4*)(hb + (size_t)sorted[e] * DOH);
        a0[0] += v.x; a0[1] += v.y; a0[2] += v.z; a0[3] += v.w;
    }
    #pragma unroll
    for (int j = 0; j < 4; ++j) {
        a0[j] += a1[j];
        a0[j] += __shfl_xor(a0[j], 32);
    }
    int deg = s1 - s0;
    float inv = 1.f / (float)(deg > 0 ? deg : 1);
    float v0 = (self.x + a0[0]) * inv;
    float v1 = (self.y + a0[1]) * inv;
    float v2 = (self.z + a0[2]) * inv;
    float v3 = (self.w + a0[3]) * inv;
    // every column's value is held by exactly 2 lanes -> divide by 2*DOH
    float mean = waveReduceSum(v0 + v1 + v2 + v3) * (1.f / (2 * DOH));
    float ex2  = waveReduceSum(v0 * v0 + v1 * v1 + v2 * v2 + v3 * v3) * (1.f / (2 * DOH));
    float rst = rsqrtf(ex2 - mean * mean + EPSV);
    float4 gv = *(const float4*)(g + li * 4);
    float4 bv = *(const float4*)(b + li * 4);
    float o0 = (v0 - mean) * rst * gv.x + bv.x;
    float o1 = (v1 - mean) * rst * gv.y + bv.y;
    float o2 = (v2 - mean) * rst * gv.z + bv.z;
    float o3 = (v3 - mean) * rst * gv.w + bv.w;
    if (half == 0) {
        ushort* row = outS + (size_t)node * 256;
        ushort h0 = f2b(o0), h1 = f2b(o1), h2 = f2b(o2), h3 = f2b(o3);
        uint2 hi, lo;
        hi.x = (uint)h0 | ((uint)h1 << 16);
        hi.y = (uint)h2 | ((uint)h3 << 16);
        lo.x = packb(o0 - b2f(h0), o1 - b2f(h1));
        lo.y = packb(o2 - b2f(h2), o3 - b2f(h3));
        *(uint2*)(row + li * 4)       = hi;
        *(uint2*)(row + 128 + li * 4) = lo;
    }
}

// LayerNorm in place on split hi|lo buffer [M,256]
__global__ __launch_bounds__(256)
void lns_k(ushort* __restrict__ hS, const float* __restrict__ g,
           const float* __restrict__ b) {
    int node = blockIdx.x * 4 + (threadIdx.x >> 6);
    if (node >= NN) return;
    int l = threadIdx.x & 63;
    ushort* row = hS + (size_t)node * 256;
    uint hh = *(uint*)(row + 2 * l);
    uint ll = *(uint*)(row + 128 + 2 * l);
    float v0 = b2f((ushort)hh) + b2f((ushort)ll);
    float v1 = b2f((ushort)(hh >> 16)) + b2f((ushort)(ll >> 16));
    float mean = waveReduceSum(v0 + v1) * (1.f / DOH);
    float ex2  = waveReduceSum(v0 * v0 + v1 * v1) * (1.f / DOH);
    float rst = rsqrtf(ex2 - mean * mean + EPSV);
    float o0 = (v0 - mean) * rst * g[2 * l] + b[2 * l];
    float o1 = (v1 - mean) * rst * g[2 * l + 1] + b[2 * l + 1];
    ushort h0 = f2b(o0), h1 = f2b(o1);
    ushort lo0 = f2b(o0 - b2f(h0)), lo1 = f2b(o1 - b2f(h1));
    *(uint*)(row + 2 * l)       = (uint)h0 | ((uint)h1 << 16);
    *(uint*)(row + 128 + 2 * l) = (uint)lo0 | ((uint)lo1 << 16);
}

// ---------------- BatchNorm stats + final classifier ----------------

__global__ __launch_bounds__(256)
void bnstat_k(const float* __restrict__ z, float* __restrict__ sums, int M) {
    int col = threadIdx.x & 63;
    int rgrp = threadIdx.x >> 6;
    float s = 0.f, s2 = 0.f;
    for (int r = blockIdx.x * 4 + rgrp; r < M; r += gridDim.x * 4) {
        float v = z[(size_t)r * DCH + col];
        s += v; s2 += v * v;
    }
    __shared__ float sh[2][4][64];
    sh[0][rgrp][col] = s;
    sh[1][rgrp][col] = s2;
    __syncthreads();
    if (rgrp == 0) {
        s  = sh[0][0][col] + sh[0][1][col] + sh[0][2][col] + sh[0][3][col];
        s2 = sh[1][0][col] + sh[1][1][col] + sh[1][2][col] + sh[1][3][col];
        atomicAdd(&sums[col], s);
        atomicAdd(&sums[64 + col], s2);
    }
}

__global__ __launch_bounds__(256)
void final_k(const float* __restrict__ z, const float* __restrict__ sums,
             const float* __restrict__ bn_g, const float* __restrict__ bn_b,
             const float* __restrict__ cW2, const float* __restrict__ cb2,
             float* __restrict__ out, int M) {
    int row = blockIdx.x * 4 + (threadIdx.x >> 6);
    int lane = threadIdx.x & 63;
    if (row >= M) return;
    float zv = z[(size_t)row * DCH + lane];
    float mean = sums[lane] * (1.f / M);
    float var = sums[64 + lane] * (1.f / M) - mean * mean;
    float zb = (zv - mean) * rsqrtf(var + EPSV) * bn_g[lane] + bn_b[lane];
    float logit[DOUT];
    #pragma unroll
    for (int o = 0; o < DOUT; ++o) {
        float p = zb * cW2[lane * DOUT + o];
        #pragma unroll
        for (int s = 32; s > 0; s >>= 1) p += __shfl_xor(p, s);
        logit[o] = p + cb2[o];
    }
    float mx = logit[0];
    #pragma unroll
    for (int o = 1; o < DOUT; ++o) mx = fmaxf(mx, logit[o]);
    float den = 0.f;
    #pragma unroll
    for (int o = 0; o < DOUT; ++o) { logit[o] = expf(logit[o] - mx); den += logit[o]; }
    float inv = 1.f / den;
    if (lane == 0) {
        #pragma unroll
        for (int o = 0; o < DOUT; ++o) out[(size_t)row * DOUT + o] = logit[o] * inv;
    }
}

// ---------------- orchestration ----------------

extern "C" void kernel_launch(void* const* d_in, const int* in_sizes, int n_in,
                              void* d_out, int out_size, void* d_ws, size_t ws_size,
                              hipStream_t stream) {
    const float* x     = (const float*)d_in[0];
    const int* eptr[4] = {(const int*)d_in[1], (const int*)d_in[2],
                          (const int*)d_in[3], (const int*)d_in[4]};
    const float* Wl0   = (const float*)d_in[5];
    const float* bl0   = (const float*)d_in[6];
    const float* Wr0   = (const float*)d_in[7];
    const float* Wl    = (const float*)d_in[8];
    const float* bl    = (const float*)d_in[9];
    const float* Wr    = (const float*)d_in[10];
    const float* lin_W = (const float*)d_in[11];
    const float* lin_b = (const float*)d_in[12];
    const float* nrm_g = (const float*)d_in[13];
    const float* nrm_b = (const float*)d_in[14];
    const float* pW1   = (const float*)d_in[15];
    const float* pb1   = (const float*)d_in[16];
    const float* pln_g = (const float*)d_in[17];
    const float* pln_b = (const float*)d_in[18];
    const float* pW2   = (const float*)d_in[19];
    const float* pb2   = (const float*)d_in[20];
    const float* cW1   = (const float*)d_in[21];
    const float* cb1   = (const float*)d_in[22];
    const float* bn_g  = (const float*)d_in[23];
    const float* bn_b  = (const float*)d_in[24];
    const float* cW2   = (const float*)d_in[25];
    const float* cb2   = (const float*)d_in[26];

    size_t wo = 0;
    auto alloc = [&](size_t bytes) -> void* {
        void* p = (char*)d_ws + wo;
        wo += (bytes + 255) & ~(size_t)255;
        return p;
    };
    int* off      = (int*)alloc(4 * OFFS * sizeof(int));
    int* cursor   = (int*)alloc(4 * NN * sizeof(int));
    ushort* sorted = (ushort*)alloc((size_t)4 * NE * sizeof(ushort));
    ushort* WBt0  = (ushort*)alloc((size_t)256 * 1280 * 2);
    ushort* WBt1  = (ushort*)alloc((size_t)256 * 2560 * 2);
    ushort* WBt2  = (ushort*)alloc((size_t)256 * 2560 * 2);
    ushort* BtLin = (ushort*)alloc((size_t)128 * 768 * 2);
    ushort* BtP1  = (ushort*)alloc((size_t)128 * 384 * 2);
    ushort* BtP2  = (ushort*)alloc((size_t)128 * 384 * 2);
    ushort* BtC1  = (ushort*)alloc((size_t)64 * 384 * 2);
    float* bsum   = (float*)alloc(3 * 256 * sizeof(float));
    float* bnsum  = (float*)alloc(128 * sizeof(float));
    ushort* aggbuf = (ushort*)alloc((size_t)ROWS * LDAGG * 2); // 102.5 MB
    ushort* hc1   = (ushort*)alloc((size_t)ROWS * 256 * 2);    // 25.6 MB
    ushort* hc2   = (ushort*)alloc((size_t)ROWS * 256 * 2);    // 25.6 MB

    // overlays (sequenced by stream order):
    float*  hL  = (float*)hc1;                                  // after hc1 dead (lin out)
    ushort* hPs = hc2;                                          // after hc2 dead (poolln out)
    ushort* hQs = aggbuf;                                       // after aggbuf/z3 dead
    ushort* hRs = (ushort*)((char*)aggbuf + ((size_t)32 << 20));
    float*  z   = (float*)((char*)aggbuf + ((size_t)64 << 20));

    const int EB = (NE + 255) / 256;      // 1-edge/thread blocks
    const int GX = (NN + 127) / 128;      // 391 MFMA row tiles
    const int AGG = (NN + 3) / 4;         // 12500

    // --- merged weight prep + xconv (independent of CSR) ---
    prep_k<<<4067 + 25000, 256, 0, stream>>>(
        Wl0, Wr0, Wl, Wr, bl0, bl, lin_W, pW1, pW2, cW1, x,
        WBt0, WBt1, WBt2, BtLin, BtP1, BtP2, BtC1, bsum, aggbuf);

    // --- CSR build ---
    hipMemsetAsync(cursor, 0, 4 * NN * sizeof(int), stream);
    count_k<<<dim3(EB, 4), 256, 0, stream>>>(eptr[0] + NE, eptr[1] + NE,
                                             eptr[2] + NE, eptr[3] + NE, cursor);
    scan_k<<<4, 1024, 0, stream>>>(cursor, off, cursor);
    scatter_k<<<dim3(EB, 4), 256, 0, stream>>>(eptr[0], eptr[1], eptr[2], eptr[3],
                                               cursor, sorted);

    // --- layer 0: gather from aggbuf+512, GEMM single-source ---
    aggrb128_k<<<dim3(AGG, 4), 256, 0, stream>>>(aggbuf + 512, off, sorted, aggbuf);
    lgemm_k<1><<<GX, 512, 0, stream>>>(
        aggbuf, LDAGG, aggbuf, LDAGG, 640, WBt0, bsum, (void*)hc1, 256, NN, 640);

    // --- layers 1,2: gather from compact hc, GEMM two-source (agg | compact h) ---
    aggrb256_k<<<dim3(AGG, 4), 256, 0, stream>>>(hc1, off, sorted, aggbuf);
    lgemm_k<1><<<GX, 512, 0, stream>>>(
        aggbuf, LDAGG, hc1, 256, 1024, WBt1, bsum + 256, (void*)hc2, 256, NN, 1280);
    aggrb256_k<<<dim3(AGG, 4), 256, 0, stream>>>(hc2, off, sorted, aggbuf);
    lgemm_k<2><<<GX, 512, 0, stream>>>(   // split z3 into aggbuf cols 0:512 (own rows)
        aggbuf, LDAGG, hc2, 256, 1024, WBt2, bsum + 512, (void*)aggbuf, LDAGG, NN, 1280);

    // --- lin head: hL fp32 = z3 @ lin_W + lin_b (split-A x split-W MFMA) ---
    mgemm_k<128, 2, false, 0><<<GX, 256, 0, stream>>>(
        aggbuf, LDAGG, aggbuf, LDAGG, 512, BtLin, lin_b, (void*)hL, DOH, NN, 768, 512);

    // --- onset pooling + LayerNorm -> hPs (split) ---
    poolln_k<<<AGG, 256, 0, stream>>>(hL, off, sorted, nrm_g, nrm_b, hPs);

    // --- pool MLP (split-A x split-W MFMA) ---
    mgemm_k<128, 2, true, 2><<<GX, 256, 0, stream>>>(
        hPs, 256, hPs, 256, 256, BtP1, pb1, (void*)hQs, 256, NN, 384, 256);
    lns_k<<<AGG, 256, 0, stream>>>(hQs, pln_g, pln_b);
    mgemm_k<128, 2, false, 2><<<GX, 256, 0, stream>>>(
        hQs, 256, hQs, 256, 256, BtP2, pb2, (void*)hRs, 256, NN, 384, 256);

    // --- classifier: z fp32 = relu(hRs @ cW1 + cb1); BN stats; final ---
    mgemm_k<64, 1, true, 0><<<GX, 128, 0, stream>>>(
        hRs, 256, hRs, 256, 256, BtC1, cb1, (void*)z, DCH, NN, 384, 256);
    hipMemsetAsync(bnsum, 0, 128 * sizeof(float), stream);
    bnstat_k<<<256, 256, 0, stream>>>(z, bnsum, NN);
    final_k<<<AGG, 256, 0, stream>>>(z, bnsum, bn_g, bn_b, cW2, cb2,
                                     (float*)d_out, NN);
}